// Round 23
// baseline (93.677 us; speedup 1.0000x reference)
//
#include <hip/hip_runtime.h>
#include <math.h>

#define NX 128
#define NY 128
#define NZ 64
#define NVOX (NX * NY * NZ)   // 1048576 = 1<<20
#define NC 32
#define FH 120
#define FW 160
#define FHW (FH * FW)         // 19200
#define VOXSZ 0.04f
#define NB 2
#define T_BYTES ((size_t)NB * FHW * NC * 4)   // 4,915,200

// Transpose features (B,C,H*W) -> T (B,H*W,C), wide (R21-proven).
__global__ __launch_bounds__(256) void transpose_feat_kernel(
    const float* __restrict__ feat, float* __restrict__ T)
{
    const int t = blockIdx.x * 256 + threadIdx.x;     // 0..307199
    const int quad = t & 7;
    const int pix  = (t >> 3) % FHW;
    const int b    = t / (FHW * 8);
    const float* fb = feat + (size_t)b * NC * FHW + pix;
    float v[4];
    #pragma unroll
    for (int q = 0; q < 4; ++q) v[q] = fb[(size_t)(4 * quad + q) * FHW];
    float4* row = (float4*)(T + ((size_t)b * FHW + pix) * NC);
    row[quad] = make_float4(v[0], v[1], v[2], v[3]);
}

// One thread per 4 z-consecutive voxels. CACHED float4 stores (the single
// untested combo: R17's store width without R17's NT poison).
// Projection = PINNED R14 pipeline (f32, contract off, pairwise association,
// IEEE div, rndne) -- bit-exact; 4 voxels share the i,j partial sums exactly
// as R14 did. XCD batch swizzle (R21): blockIdx%8 {0..3}->b0, {4..7}->b1.
__global__ __launch_bounds__(256) void voxel_backproject_kernel(
    const float* __restrict__ proj,
    const float* __restrict__ T,
    const float* __restrict__ origin,
    float* __restrict__ out)
{
#pragma clang fp contract(off)
    const int t  = threadIdx.x;
    const int q8 = blockIdx.x >> 3;                   // 0..255
    const int r8 = blockIdx.x & 7;
    const int b  = r8 >> 2;
    const int g  = q8 * 4 + (r8 & 3);                 // 0..1023 within batch
    const int n0 = g * 1024 + t * 4;                  // first voxel of quad
    const int i  = n0 >> 13;
    const int j  = (n0 >> 6) & (NY - 1);
    const int k0 = n0 & (NZ - 1);

    const float* P = proj + b * 12;
    const float ox = origin[b * 3 + 0];
    const float oy = origin[b * 3 + 1];
    const float oz = origin[b * 3 + 2];

    const float wx = (float)i * VOXSZ + ox;
    const float wy = (float)j * VOXSZ + oy;

    const float tx = P[0] * wx + P[1] * wy;
    const float ty = P[4] * wx + P[5] * wy;
    const float tz = P[8] * wx + P[9] * wy;

    bool vld[4];
    const float4* rowp[4];
    float vmp[4];

    #pragma unroll
    for (int q = 0; q < 4; ++q) {
        const float wz = (float)(k0 + q) * VOXSZ + oz;
        const float cx = tx + (P[2]  * wz + P[3]);
        const float cy = ty + (P[6]  * wz + P[7]);
        const float cz = tz + (P[10] * wz + P[11]);
        const float qx = cx / cz;
        const float qy = cy / cz;
        const int px = __float2int_rn(qx);
        const int py = __float2int_rn(qy);
        const bool v = (px >= 0) & (py >= 0) & (px < FW) & (py < FH) & (cz > 0.0f);
        vld[q] = v;
        vmp[q] = v ? 1.0f : 0.0f;
        const int idx = v ? (py * FW + px) : 0;
        rowp[q] = (const float4*)(T + ((size_t)b * FHW + idx) * NC);
    }

    float* ob = out + (size_t)b * NC * NVOX + n0;
    const bool any = vld[0] | vld[1] | vld[2] | vld[3];
    const float4 z4 = {0,0,0,0};

    if (any) {
        #pragma unroll
        for (int r = 0; r < 8; ++r) {
            const float4 q0 = vld[0] ? rowp[0][r] : z4;
            const float4 q1 = vld[1] ? rowp[1][r] : z4;
            const float4 q2 = vld[2] ? rowp[2][r] : z4;
            const float4 q3 = vld[3] ? rowp[3][r] : z4;
            const float4 s0 = {q0.x, q1.x, q2.x, q3.x};
            const float4 s1 = {q0.y, q1.y, q2.y, q3.y};
            const float4 s2 = {q0.z, q1.z, q2.z, q3.z};
            const float4 s3 = {q0.w, q1.w, q2.w, q3.w};
            *(float4*)(ob + (size_t)(4*r + 0) * NVOX) = s0;
            *(float4*)(ob + (size_t)(4*r + 1) * NVOX) = s1;
            *(float4*)(ob + (size_t)(4*r + 2) * NVOX) = s2;
            *(float4*)(ob + (size_t)(4*r + 3) * NVOX) = s3;
        }
    } else {
        #pragma unroll
        for (int c = 0; c < NC; ++c)
            *(float4*)(ob + (size_t)c * NVOX) = z4;
    }

    float* vout = out + (size_t)NB * NC * NVOX + (size_t)b * NVOX + n0;
    *(float4*)vout = make_float4(vmp[0], vmp[1], vmp[2], vmp[3]);
}

extern "C" void kernel_launch(void* const* d_in, const int* in_sizes, int n_in,
                              void* d_out, int out_size, void* d_ws, size_t ws_size,
                              hipStream_t stream) {
    const float* proj   = (const float*)d_in[0];
    const float* feat   = (const float*)d_in[1];
    const float* origin = (const float*)d_in[2];
    float* out = (float*)d_out;

    float* T = (float*)d_ws;
    transpose_feat_kernel<<<(NB * FHW * 8) / 256, 256, 0, stream>>>(feat, T);
    const int total_threads = NB * (NVOX / 4);        // 524288
    voxel_backproject_kernel<<<total_threads / 256, 256, 0, stream>>>(proj, T, origin, out);
}